// Round 8
// baseline (171.301 us; speedup 1.0000x reference)
//
#include <hip/hip_runtime.h>
#include <math.h>

// B=64, ROWS=7, COLS=7, D=1280, H=256, S=5, NEG=16, GRU_ROWS=6
// valid (s,r): r < 6-s -> 20 pairs; num_preds = 20*64*7 = 8960

typedef __bf16 bf16x8 __attribute__((ext_vector_type(8)));
typedef float  f32x4  __attribute__((ext_vector_type(4)));
typedef unsigned short u16;
typedef unsigned int u32;

__device__ inline u16 f2bf(float f) {           // RNE f32 -> bf16 bits
  unsigned int u = __float_as_uint(f);
  u += 0x7fff + ((u >> 16) & 1);
  return (u16)(u >> 16);
}

__device__ inline void f2bf8(const float* s, u16* o) {
  float4 v0 = *(const float4*)s, v1 = *(const float4*)(s + 4);
  o[0] = f2bf(v0.x); o[1] = f2bf(v0.y); o[2] = f2bf(v0.z); o[3] = f2bf(v0.w);
  o[4] = f2bf(v1.x); o[5] = f2bf(v1.y); o[6] = f2bf(v1.z); o[7] = f2bf(v1.w);
}

__device__ inline bf16x8 lds_frag(const char* sm, int off) {
  return __builtin_bit_cast(bf16x8, *(const uint4*)(sm + off));
}

// async global->LDS 16B per lane (wave-uniform LDS base, per-lane global src)
__device__ inline void gld_lds16(const void* g, void* l) {
  __builtin_amdgcn_global_load_lds(
      (const __attribute__((address_space(1))) u32*)g,
      (__attribute__((address_space(3))) u32*)l, 16, 0, 0);
}

#define MFMA16(a, b, c) __builtin_amdgcn_mfma_f32_16x16x32_bf16(a, b, c, 0, 0, 0)

// ---------------------------------------------------------------------------
// pack_all: one pass producing all three per-lane fragment-ordered bf16
// buffers (each wave's fragment load in the consumers is one contiguous,
// coalesced 1KB global_load_dwordx4 — no LDS staging needed):
//  whhpk: w_hh gate-interleaved GRU fragments  (24576 thr)
//  wkwpk: wk_w GEMM1 B-fragments, frag f=((s*20+ch)*4+w)*8+ks  (204800 thr)
//  epk:   enc  GEMM2 B-fragments, frag f=((b*20+ch)*4+w)*2+ks2 (655360 thr)
// ---------------------------------------------------------------------------
__global__ __launch_bounds__(256) void pack_all(
    const float* __restrict__ w_hh, const float* __restrict__ wk_w,
    const float* __restrict__ enc,
    u16* __restrict__ whhpk, u16* __restrict__ wkwpk, u16* __restrict__ epk)
{
  int tid = blockIdx.x * 256 + threadIdx.x;
  int lane = tid & 63;
  u16 o[8];
  if (tid < 24576) {
    int rest = tid >> 6;                       // cb*8 + ks
    int cb = rest >> 3, ks = rest & 7;
    int w = cb / 6, nf = cb % 6;
    int g = nf >> 1, half = nf & 1;
    int col = g * 256 + w * 32 + half * 16 + (lane & 15);
    int k = ks * 32 + (lane >> 4) * 8;
    f2bf8(&w_hh[(size_t)col * 256 + k], o);
    *(uint4*)&whhpk[(size_t)tid * 8] = *(uint4*)o;
  } else if (tid < 229376) {
    int u = tid - 24576;
    int f = u >> 6;
    int ks = f & 7, t1 = f >> 3;
    int w = t1 & 3, t2 = t1 >> 2;
    int ch = t2 % 20, s = t2 / 20;
    f2bf8(&wk_w[((size_t)s * 1280 + ch * 64 + w * 16 + (lane & 15)) * 256
                + ks * 32 + (lane >> 4) * 8], o);
    *(uint4*)&wkwpk[(size_t)f * 512 + lane * 8] = *(uint4*)o;
  } else if (tid < 884736) {
    int u = tid - 229376;
    int f = u >> 6;
    int ks2 = f & 1, t1 = f >> 1;
    int w = t1 & 3, t2 = t1 >> 2;
    int ch = t2 % 20, b = t2 / 20;
    int q = w * 16 + (lane & 15);
    if (q < 49) {
      f2bf8(&enc[(size_t)(b * 49 + q) * 1280 + ch * 64 + ks2 * 32 + (lane >> 4) * 8], o);
    } else {
#pragma unroll
      for (int j = 0; j < 8; ++j) o[j] = 0;
    }
    *(uint4*)&epk[(size_t)f * 512 + lane * 8] = *(uint4*)o;
  }
}

// ---------------------------------------------------------------------------
// gi = enc @ w_ih^T + b_ih via bf16 MFMA, f32->bf16 conversion INLINE during
// LDS staging (encb/wihb buffers and the cvt pass are gone).
// C[2688][768], K=1280. Grid (6,21), 256 thr = 4 waves (2x2), BK=64.
// ---------------------------------------------------------------------------
__global__ __launch_bounds__(256) void gi_mfma(
    const float* __restrict__ enc, const float* __restrict__ w_ih,
    const float* __restrict__ b_ih, float* __restrict__ gi)
{
  const int bx = blockIdx.x, by = blockIdx.y;
  const int t = threadIdx.x, lane = t & 63, w = t >> 6;
  const int wr = w >> 1, wc = w & 1;

  __shared__ char sm[32768];
  const int A_OFF = 0, B_OFF = 16384;

  f32x4 acc[4][4];
#pragma unroll
  for (int i = 0; i < 4; ++i)
#pragma unroll
    for (int j = 0; j < 4; ++j) acc[i][j] = (f32x4){0.f, 0.f, 0.f, 0.f};

  for (int k0 = 0; k0 < 1280; k0 += 64) {
    if (k0) __syncthreads();
#pragma unroll
    for (int j = 0; j < 4; ++j) {
      int u = j * 256 + t;
      int row = u >> 3, slot = u & 7;
      int m = by * 128 + row;
      int r = m / 448, n = m - r * 448;
      int b = n / 7, c = n - b * 7;
      u16 o[8];
      f2bf8(&enc[(size_t)(b * 49 + r * 7 + c) * 1280 + k0 + slot * 8], o);
      *(uint4*)(sm + A_OFF + row * 128 + ((slot * 16) ^ ((row & 7) << 4))) = *(uint4*)o;
    }
#pragma unroll
    for (int j = 0; j < 4; ++j) {
      int u = j * 256 + t;
      int row = u >> 3, slot = u & 7;
      u16 o[8];
      f2bf8(&w_ih[(size_t)(bx * 128 + row) * 1280 + k0 + slot * 8], o);
      *(uint4*)(sm + B_OFF + row * 128 + ((slot * 16) ^ ((row & 7) << 4))) = *(uint4*)o;
    }
    __syncthreads();
#pragma unroll
    for (int ks = 0; ks < 2; ++ks) {
      bf16x8 a[4], b[4];
#pragma unroll
      for (int i = 0; i < 4; ++i) {
        int arow = wr * 64 + i * 16 + (lane & 15);
        int akb  = (ks * 64 + (lane >> 4) * 16) ^ ((arow & 7) << 4);
        a[i] = lds_frag(sm, A_OFF + arow * 128 + akb);
        int brow = wc * 64 + i * 16 + (lane & 15);
        int bkb  = (ks * 64 + (lane >> 4) * 16) ^ ((brow & 7) << 4);
        b[i] = lds_frag(sm, B_OFF + brow * 128 + bkb);
      }
#pragma unroll
      for (int i = 0; i < 4; ++i)
#pragma unroll
        for (int jn = 0; jn < 4; ++jn)
          acc[i][jn] = MFMA16(a[i], b[jn], acc[i][jn]);
    }
  }

#pragma unroll
  for (int i = 0; i < 4; ++i)
#pragma unroll
    for (int jn = 0; jn < 4; ++jn) {
      int gcol = bx * 128 + wc * 64 + jn * 16 + (lane & 15);
      float bias = b_ih[gcol];
#pragma unroll
      for (int r4 = 0; r4 < 4; ++r4) {
        int grow = by * 128 + wr * 64 + i * 16 + (lane >> 4) * 4 + r4;
        gi[(size_t)grow * 768 + gcol] = acc[i][jn][r4] + bias;
      }
    }
}

// ---------------------------------------------------------------------------
// GRU (unchanged from round 7 — it works): 28 blocks x 512 thr, weights
// streamed via 2-stage register pipeline, gi async-staged into LDS dbuf.
// ---------------------------------------------------------------------------
__global__ __launch_bounds__(512) void gru_fused(
    const u16* __restrict__ whh_pk, const float* __restrict__ b_hh,
    const float* __restrict__ hidden, const float* __restrict__ gi,
    u16* __restrict__ ctxb)
{
  const int n0 = blockIdx.x * 16;
  const int t = threadIdx.x, lane = t & 63, w = t >> 6;

  __shared__ char sm[16384 + 2 * 49152];
  const int GI0 = 16384;

  const int l15 = lane & 15;
  const int seq0 = (lane >> 4) * 4;
  const int hc0 = w * 32 + l15, hc1 = w * 32 + 16 + l15;

  const float br0 = b_hh[hc0],       br1 = b_hh[hc1];
  const float bz0 = b_hh[256 + hc0], bz1 = b_hh[256 + hc1];
  const float bn0 = b_hh[512 + hc0], bn1 = b_hh[512 + hc1];

#pragma unroll
  for (int i = 0; i < 6; ++i) {
    int chunk = w * 6 + i;
    gld_lds16(gi + (size_t)n0 * 768 + chunk * 256 + lane * 4,
              sm + GI0 + chunk * 1024);
  }

  float hold[2][4];
  {
    float h0 = hidden[hc0], h1 = hidden[hc1];
#pragma unroll
    for (int r4 = 0; r4 < 4; ++r4) { hold[0][r4] = h0; hold[1][r4] = h1; }
    u16 hb0 = f2bf(h0), hb1 = f2bf(h1);
#pragma unroll
    for (int r4 = 0; r4 < 4; ++r4) {
      int seq = seq0 + r4;
      *(u16*)(sm + seq * 512 + ((hc0 * 2) ^ ((seq & 7) << 4))) = hb0;
      *(u16*)(sm + seq * 512 + ((hc1 * 2) ^ ((seq & 7) << 4))) = hb1;
    }
  }
  __syncthreads();

  for (int r = 0; r < 6; ++r) {
    const char* hb  = sm + (r & 1) * 8192;
    char* hbn       = sm + ((r + 1) & 1) * 8192;
    const char* gbr = sm + GI0 + (r & 1) * 49152;

    if (r + 1 < 6) {
#pragma unroll
      for (int i = 0; i < 6; ++i) {
        int chunk = w * 6 + i;
        gld_lds16(gi + (size_t)((r + 1) * 448 + n0) * 768 + chunk * 256 + lane * 4,
                  sm + GI0 + ((r + 1) & 1) * 49152 + chunk * 1024);
      }
    }

    uintptr_t pa = (uintptr_t)whh_pk;
    asm volatile("" : "+v"(pa));
    const char* pkb = (const char*)pa + w * 49152 + lane * 16;

    f32x4 acc[6];
#pragma unroll
    for (int nf = 0; nf < 6; ++nf) acc[nf] = (f32x4){0.f, 0.f, 0.f, 0.f};

    bf16x8 bA[6], bB[6];
#pragma unroll
    for (int nf = 0; nf < 6; ++nf) bA[nf] = *(const bf16x8*)(pkb + nf * 8192);
#pragma unroll
    for (int kp = 0; kp < 4; ++kp) {
      const int ks0 = kp * 2, ks1 = kp * 2 + 1;
#pragma unroll
      for (int nf = 0; nf < 6; ++nf)
        bB[nf] = *(const bf16x8*)(pkb + nf * 8192 + ks1 * 1024);
      {
        bf16x8 a = lds_frag(hb, l15 * 512 +
                            ((ks0 * 64 + (lane >> 4) * 16) ^ ((l15 & 7) << 4)));
#pragma unroll
        for (int nf = 0; nf < 6; ++nf) acc[nf] = MFMA16(a, bA[nf], acc[nf]);
      }
      if (kp < 3) {
#pragma unroll
        for (int nf = 0; nf < 6; ++nf)
          bA[nf] = *(const bf16x8*)(pkb + nf * 8192 + (ks0 + 2) * 1024);
      }
      {
        bf16x8 a = lds_frag(hb, l15 * 512 +
                            ((ks1 * 64 + (lane >> 4) * 16) ^ ((l15 & 7) << 4)));
#pragma unroll
        for (int nf = 0; nf < 6; ++nf) acc[nf] = MFMA16(a, bB[nf], acc[nf]);
      }
    }

    __syncthreads();

#pragma unroll
    for (int r4 = 0; r4 < 4; ++r4) {
      int seq = seq0 + r4;
      float ir0 = *(const float*)(gbr + (size_t)(seq * 768 + hc0) * 4);
      float iz0 = *(const float*)(gbr + (size_t)(seq * 768 + 256 + hc0) * 4);
      float in0 = *(const float*)(gbr + (size_t)(seq * 768 + 512 + hc0) * 4);
      float ir1 = *(const float*)(gbr + (size_t)(seq * 768 + hc1) * 4);
      float iz1 = *(const float*)(gbr + (size_t)(seq * 768 + 256 + hc1) * 4);
      float in1 = *(const float*)(gbr + (size_t)(seq * 768 + 512 + hc1) * 4);
      {
        float rg = 1.f / (1.f + expf(-(ir0 + acc[0][r4] + br0)));
        float zg = 1.f / (1.f + expf(-(iz0 + acc[2][r4] + bz0)));
        float ng = tanhf(in0 + rg * (acc[4][r4] + bn0));
        float hnew = (1.f - zg) * ng + zg * hold[0][r4];
        hold[0][r4] = hnew;
        u16 hb16 = f2bf(hnew);
        *(u16*)(hbn + seq * 512 + ((hc0 * 2) ^ ((seq & 7) << 4))) = hb16;
        ctxb[(size_t)(r * 448 + n0 + seq) * 256 + hc0] = hb16;
      }
      {
        float rg = 1.f / (1.f + expf(-(ir1 + acc[1][r4] + br1)));
        float zg = 1.f / (1.f + expf(-(iz1 + acc[3][r4] + bz1)));
        float ng = tanhf(in1 + rg * (acc[5][r4] + bn1));
        float hnew = (1.f - zg) * ng + zg * hold[1][r4];
        hold[1][r4] = hnew;
        u16 hb16 = f2bf(hnew);
        *(u16*)(hbn + seq * 512 + ((hc1 * 2) ^ ((seq & 7) << 4))) = hb16;
        ctxb[(size_t)(r * 448 + n0 + seq) * 256 + hc1] = hb16;
      }
    }
    __syncthreads();
  }
}

// ---------------------------------------------------------------------------
// Fused preds+dots v2: W and E read REGISTER-DIRECT from pre-packed
// fragment-ordered global buffers (L2-hot, coalesced 1KB/wave) — no W/E LDS
// staging, no staging barriers. Only P goes through LDS (GEMM1->GEMM2
// transpose), double-buffered -> exactly ONE barrier per chunk.
// LDS 36864 (was 71680) -> 4 blocks/CU.
// ---------------------------------------------------------------------------
__global__ __launch_bounds__(256) void fused_pd(
    const u16* __restrict__ ctxb, const u16* __restrict__ wkwpk,
    const float* __restrict__ wk_b, const u16* __restrict__ epk,
    float* __restrict__ dots)
{
  const int b = blockIdx.x;
  const int s = blockIdx.y;
  const int Ms = (6 - s) * 7;
  const int t = threadIdx.x;
  const int lane = t & 63, w = t >> 6;

  __shared__ uint4 smem4[36864 / 16];   // ctx 24576 | Pt dbuf 2x6144
  char* sm = (char*)smem4;
  const int PT_OFF = 24576;

  // stage ctx once (48 rows x 256 h bf16), swizzled
#pragma unroll
  for (int j = 0; j < 6; ++j) {
    int u = j * 256 + t;
    int row = u >> 5, slot = u & 31;
    int rr = row < Ms ? row : 0;
    int r = rr / 7, c = rr - r * 7;
    uint4 v = *(const uint4*)&ctxb[((size_t)(r * 448 + b * 7 + c)) * 256 + slot * 8];
    int off = row * 512 + ((slot * 16) ^ ((row & 7) << 4));
    *(uint4*)(sm + off) = v;
  }
  __syncthreads();

  // hoist A1 fragments (step-invariant across all 20 chunks)
  bf16x8 a1[3][8];
#pragma unroll
  for (int m = 0; m < 3; ++m)
#pragma unroll
    for (int ks = 0; ks < 8; ++ks) {
      int row = m * 16 + (lane & 15);
      int kb  = (ks * 64 + (lane >> 4) * 16) ^ ((row & 7) << 4);
      a1[m][ks] = lds_frag(sm, row * 512 + kb);
    }

  f32x4 acc2[3];
#pragma unroll
  for (int m = 0; m < 3; ++m) acc2[m] = (f32x4){0.f, 0.f, 0.f, 0.f};

  const char* wfB = (const char*)wkwpk + ((size_t)(s * 20) * 4 + w) * 8192 + lane * 16;
  const char* efB = (const char*)epk   + ((size_t)(b * 20) * 4 + w) * 2048 + lane * 16;
  const int colL = w * 16 + (lane & 15);

  for (int ch = 0; ch < 20; ++ch) {
    const char* wf = wfB + (size_t)ch * 4 * 8192;
    char* pt = sm + PT_OFF + (ch & 1) * 6144;

    // GEMM1: P[48][64] = ctx . Wchunk^T  (W frags register-direct from L2)
    f32x4 acc1[3];
#pragma unroll
    for (int m = 0; m < 3; ++m) acc1[m] = (f32x4){0.f, 0.f, 0.f, 0.f};
#pragma unroll
    for (int ks = 0; ks < 8; ++ks) {
      bf16x8 bW = *(const bf16x8*)(wf + ks * 1024);
      acc1[0] = MFMA16(a1[0][ks], bW, acc1[0]);
      acc1[1] = MFMA16(a1[1][ks], bW, acc1[1]);
      acc1[2] = MFMA16(a1[2][ks], bW, acc1[2]);
    }
    // epilogue: +bias, clip, ->bf16 into Pt[ch&1]
    {
      float bias = wk_b[s * 1280 + ch * 64 + colL];
#pragma unroll
      for (int m = 0; m < 3; ++m)
#pragma unroll
        for (int r4 = 0; r4 < 4; ++r4) {
          float p = acc1[m][r4] + bias;
          p = fminf(fmaxf(p, -1.f), 1.f);
          int prow = m * 16 + (lane >> 4) * 4 + r4;
          *(u16*)(pt + prow * 128 + ((colL * 2) ^ ((prow & 7) << 4))) = f2bf(p);
        }
    }
    __syncthreads();   // Pt[ch&1] visible; dbuf makes this the ONLY barrier

    // GEMM2: dots += P . Echunk^T  (E frags register-direct from L2)
    const char* ef = efB + (size_t)ch * 4 * 2048;
#pragma unroll
    for (int ks2 = 0; ks2 < 2; ++ks2) {
      bf16x8 eB = *(const bf16x8*)(ef + ks2 * 1024);
#pragma unroll
      for (int m = 0; m < 3; ++m) {
        int prow = m * 16 + (lane & 15);
        bf16x8 pf = lds_frag(pt, prow * 128 +
                             ((ks2 * 64 + (lane >> 4) * 16) ^ ((prow & 7) << 4)));
        acc2[m] = MFMA16(pf, eB, acc2[m]);
      }
    }
  }

  // store dots [64][5][42][49]
#pragma unroll
  for (int m = 0; m < 3; ++m)
#pragma unroll
    for (int r4 = 0; r4 < 4; ++r4) {
      int row = m * 16 + (lane >> 4) * 4 + r4;
      int q = w * 16 + (lane & 15);
      if (row < Ms && q < 49)
        dots[((size_t)(b * 5 + s) * 42 + row) * 49 + q] = acc2[m][r4];
    }
}

// ---------------------------------------------------------------------------
// Loss + accuracy -> directly into d_out[2] (pre-zeroed), scaled by 1/8960
// ---------------------------------------------------------------------------
__global__ __launch_bounds__(256) void loss_kernel(
    const float* __restrict__ dots, const int* __restrict__ neg_rows,
    const int* __restrict__ neg_cols, float* __restrict__ out)
{
  int gid = blockIdx.x * 256 + threadIdx.x;
  float lsum = 0.f, csum = 0.f;
  if (gid < 8960) {
    int b = gid / 140;
    int rem = gid % 140;
    int p = rem / 7, c = rem % 7;
    int s, r;
    if      (p < 6)  { s = 0; r = p; }
    else if (p < 11) { s = 1; r = p - 6; }
    else if (p < 15) { s = 2; r = p - 11; }
    else if (p < 18) { s = 3; r = p - 15; }
    else             { s = 4; r = p - 18; }

    const float* drow = &dots[((size_t)(b * 5 + s) * 42 + r * 7 + c) * 49];
    float d[17];
    d[0] = drow[r * 7 + c];
    const int nbase = (((b * 5 + s) * 6 + r) * 7 + c) * 16;
#pragma unroll
    for (int j = 0; j < 16; ++j) {
      int q = neg_rows[nbase + j] * 7 + neg_cols[nbase + j];
      d[1 + j] = drow[q];
    }
    float m = d[0];
#pragma unroll
    for (int j = 1; j < 17; ++j) m = fmaxf(m, d[j]);
    float se = 0.f;
#pragma unroll
    for (int j = 0; j < 17; ++j) se += expf(d[j] - m);
    lsum = -(d[0] - m - logf(se));
    csum = (d[0] >= m) ? 1.f : 0.f;
  }

#pragma unroll
  for (int off = 32; off > 0; off >>= 1) {
    lsum += __shfl_down(lsum, off);
    csum += __shfl_down(csum, off);
  }
  __shared__ float red[8];
  int wid = threadIdx.x >> 6;
  if ((threadIdx.x & 63) == 0) { red[wid * 2] = lsum; red[wid * 2 + 1] = csum; }
  __syncthreads();
  if (threadIdx.x == 0) {
    atomicAdd(&out[0], (red[0] + red[2] + red[4] + red[6]) * (1.f / 8960.f));
    atomicAdd(&out[1], (red[1] + red[3] + red[5] + red[7]) * (1.f / 8960.f));
  }
}

// ---------------------------------------------------------------------------
extern "C" void kernel_launch(void* const* d_in, const int* in_sizes, int n_in,
                              void* d_out, int out_size, void* d_ws, size_t ws_size,
                              hipStream_t stream)
{
  const float* enc    = (const float*)d_in[0];
  const float* hidden = (const float*)d_in[1];
  const float* w_ih   = (const float*)d_in[2];
  const float* w_hh   = (const float*)d_in[3];
  const float* b_ih   = (const float*)d_in[4];
  const float* b_hh   = (const float*)d_in[5];
  const float* wk_w   = (const float*)d_in[6];
  const float* wk_b   = (const float*)d_in[7];
  const int* neg_rows = (const int*)d_in[8];
  const int* neg_cols = (const int*)d_in[9];
  float* out = (float*)d_out;

  float* ws    = (float*)d_ws;
  float* gi    = ws;                                // [6*448][768] f32
  u16*   ctxb  = (u16*)(gi + 6 * 448 * 768);        // [6*448][256] bf16
  u16*   whhpk = ctxb + 6 * 448 * 256;              // 196608 bf16 packed
  u16*   wkwpk = whhpk + 24576 * 8;                 // 1638400 bf16 packed
  u16*   epk   = wkwpk + 204800 * 8;                // 5242880 bf16 packed
  float* dotsb = (float*)(epk + 655360 * 8);        // [64][5][42][49] f32

  hipMemsetAsync(out, 0, 2 * sizeof(float), stream);

  pack_all<<<3456, 256, 0, stream>>>(w_hh, wk_w, enc, whhpk, wkwpk, epk);

  gi_mfma<<<dim3(6, 21), 256, 0, stream>>>(enc, w_ih, b_ih, gi);

  gru_fused<<<28, 512, 0, stream>>>(whhpk, b_hh, hidden, gi, ctxb);

  fused_pd<<<dim3(64, 5), 256, 0, stream>>>(ctxb, wkwpk, wk_b, epk, dotsb);

  loss_kernel<<<35, 256, 0, stream>>>(dotsb, neg_rows, neg_cols, out);
}

// Round 9
// 127.342 us; speedup vs baseline: 1.3452x; 1.3452x over previous
//
#include <hip/hip_runtime.h>
#include <math.h>

// B=64, ROWS=7, COLS=7, D=1280, H=256, S=5, NEG=16, GRU_ROWS=6
// valid (s,r): r < 6-s -> 20 pairs; num_preds = 20*64*7 = 8960

typedef __bf16 bf16x8 __attribute__((ext_vector_type(8)));
typedef float  f32x4  __attribute__((ext_vector_type(4)));
typedef unsigned short u16;
typedef unsigned int u32;

__device__ inline u16 f2bf(float f) {           // RNE f32 -> bf16 bits
  unsigned int u = __float_as_uint(f);
  u += 0x7fff + ((u >> 16) & 1);
  return (u16)(u >> 16);
}

__device__ inline void f2bf8(const float* s, u16* o) {
  float4 v0 = *(const float4*)s, v1 = *(const float4*)(s + 4);
  o[0] = f2bf(v0.x); o[1] = f2bf(v0.y); o[2] = f2bf(v0.z); o[3] = f2bf(v0.w);
  o[4] = f2bf(v1.x); o[5] = f2bf(v1.y); o[6] = f2bf(v1.z); o[7] = f2bf(v1.w);
}

__device__ inline bf16x8 lds_frag(const char* sm, int off) {
  return __builtin_bit_cast(bf16x8, *(const uint4*)(sm + off));
}

// async global->LDS 16B per lane (wave-uniform LDS base, per-lane global src)
__device__ inline void gld_lds16(const void* g, void* l) {
  __builtin_amdgcn_global_load_lds(
      (const __attribute__((address_space(1))) u32*)g,
      (__attribute__((address_space(3))) u32*)l, 16, 0, 0);
}

#define MFMA16(a, b, c) __builtin_amdgcn_mfma_f32_16x16x32_bf16(a, b, c, 0, 0, 0)

// ---------------------------------------------------------------------------
// pack_all: one pass producing all fragment/staging-ordered bf16 buffers.
//  whhpk: w_hh gate-interleaved GRU fragments                (24576 thr)
//  wkwpk: wk_w GEMM1 B-frags f=((s*20+ch)*4+w)*8+ks          (204800 thr)
//  epk:   enc  GEMM2 B-frags f=((b*20+ch)*4+w)*2+ks2         (655360 thr)
//  enc2:  gi_mfma A tiles [by=21][k0=20][row*8+sl] PRE-SWIZZLED
//         (slot = sl^(row&7)) so global_load_lds + linear LDS dest works
//                                                            (430080 thr)
//  wih2:  gi_mfma B tiles [bx=6][k0=20][row*8+sl] same       (122880 thr)
// ---------------------------------------------------------------------------
__global__ __launch_bounds__(256) void pack_all(
    const float* __restrict__ w_hh, const float* __restrict__ wk_w,
    const float* __restrict__ enc,  const float* __restrict__ w_ih,
    u16* __restrict__ whhpk, u16* __restrict__ wkwpk, u16* __restrict__ epk,
    u16* __restrict__ enc2,  u16* __restrict__ wih2)
{
  int tid = blockIdx.x * 256 + threadIdx.x;
  int lane = tid & 63;
  u16 o[8];
  if (tid < 24576) {
    int rest = tid >> 6;                       // cb*8 + ks
    int cb = rest >> 3, ks = rest & 7;
    int w = cb / 6, nf = cb % 6;
    int g = nf >> 1, half = nf & 1;
    int col = g * 256 + w * 32 + half * 16 + (lane & 15);
    int k = ks * 32 + (lane >> 4) * 8;
    f2bf8(&w_hh[(size_t)col * 256 + k], o);
    *(uint4*)&whhpk[(size_t)tid * 8] = *(uint4*)o;
  } else if (tid < 229376) {
    int u = tid - 24576;
    int f = u >> 6;
    int ks = f & 7, t1 = f >> 3;
    int w = t1 & 3, t2 = t1 >> 2;
    int ch = t2 % 20, s = t2 / 20;
    f2bf8(&wk_w[((size_t)s * 1280 + ch * 64 + w * 16 + (lane & 15)) * 256
                + ks * 32 + (lane >> 4) * 8], o);
    *(uint4*)&wkwpk[(size_t)f * 512 + lane * 8] = *(uint4*)o;
  } else if (tid < 884736) {
    int u = tid - 229376;
    int f = u >> 6;
    int ks2 = f & 1, t1 = f >> 1;
    int w = t1 & 3, t2 = t1 >> 2;
    int ch = t2 % 20, b = t2 / 20;
    int q = w * 16 + (lane & 15);
    if (q < 49) {
      f2bf8(&enc[(size_t)(b * 49 + q) * 1280 + ch * 64 + ks2 * 32 + (lane >> 4) * 8], o);
    } else {
#pragma unroll
      for (int j = 0; j < 8; ++j) o[j] = 0;
    }
    *(uint4*)&epk[(size_t)f * 512 + lane * 8] = *(uint4*)o;
  } else if (tid < 1314816) {
    int u = tid - 884736;                      // (by*20+k0)*1024 + row*8 + sl
    int unit = u & 1023;
    int row = unit >> 3, sl = unit & 7;
    int tk = u >> 10;
    int k0 = tk % 20, by = tk / 20;
    int m = by * 128 + row;
    int r = m / 448, n = m - r * 448;
    int b = n / 7, c = n - b * 7;
    int slot = sl ^ (row & 7);                 // inverse-swizzle the source
    f2bf8(&enc[(size_t)(b * 49 + r * 7 + c) * 1280 + k0 * 64 + slot * 8], o);
    *(uint4*)&enc2[(size_t)u * 8] = *(uint4*)o;
  } else if (tid < 1437696) {
    int u = tid - 1314816;                     // (bx*20+k0)*1024 + row*8 + sl
    int unit = u & 1023;
    int row = unit >> 3, sl = unit & 7;
    int tk = u >> 10;
    int k0 = tk % 20, bx = tk / 20;
    int slot = sl ^ (row & 7);
    f2bf8(&w_ih[(size_t)(bx * 128 + row) * 1280 + k0 * 64 + slot * 8], o);
    *(uint4*)&wih2[(size_t)u * 8] = *(uint4*)o;
  }
}

// ---------------------------------------------------------------------------
// gi = enc @ w_ih^T + b_ih via bf16 MFMA, operands pre-swizzled in global
// (enc2/wih2) -> staging is pure global_load_lds (no reg round-trip, no VALU).
// C[2688][768], K=1280. Grid (6,21), 256 thr = 4 waves (2x2), BK=64.
// ---------------------------------------------------------------------------
__global__ __launch_bounds__(256) void gi_mfma(
    const u16* __restrict__ enc2, const u16* __restrict__ wih2,
    const float* __restrict__ b_ih, float* __restrict__ gi)
{
  const int bx = blockIdx.x, by = blockIdx.y;
  const int t = threadIdx.x, lane = t & 63, w = t >> 6;
  const int wr = w >> 1, wc = w & 1;

  __shared__ char sm[32768];
  const int A_OFF = 0, B_OFF = 16384;
  const int wu = t & ~63;   // wave-uniform thread base

  f32x4 acc[4][4];
#pragma unroll
  for (int i = 0; i < 4; ++i)
#pragma unroll
    for (int j = 0; j < 4; ++j) acc[i][j] = (f32x4){0.f, 0.f, 0.f, 0.f};

  for (int k0c = 0; k0c < 20; ++k0c) {
    if (k0c) __syncthreads();
    const char* ga = (const char*)enc2 + ((size_t)(by * 20 + k0c) << 14);
    const char* gb = (const char*)wih2 + ((size_t)(bx * 20 + k0c) << 14);
#pragma unroll
    for (int j = 0; j < 4; ++j) {
      gld_lds16(ga + (j * 256 + t) * 16, sm + A_OFF + (j * 256 + wu) * 16);
      gld_lds16(gb + (j * 256 + t) * 16, sm + B_OFF + (j * 256 + wu) * 16);
    }
    __syncthreads();   // implicit vmcnt(0) drain covers global_load_lds
#pragma unroll
    for (int ks = 0; ks < 2; ++ks) {
      bf16x8 a[4], b[4];
#pragma unroll
      for (int i = 0; i < 4; ++i) {
        int arow = wr * 64 + i * 16 + (lane & 15);
        int akb  = (ks * 64 + (lane >> 4) * 16) ^ ((arow & 7) << 4);
        a[i] = lds_frag(sm, A_OFF + arow * 128 + akb);
        int brow = wc * 64 + i * 16 + (lane & 15);
        int bkb  = (ks * 64 + (lane >> 4) * 16) ^ ((brow & 7) << 4);
        b[i] = lds_frag(sm, B_OFF + brow * 128 + bkb);
      }
#pragma unroll
      for (int i = 0; i < 4; ++i)
#pragma unroll
        for (int jn = 0; jn < 4; ++jn)
          acc[i][jn] = MFMA16(a[i], b[jn], acc[i][jn]);
    }
  }

#pragma unroll
  for (int i = 0; i < 4; ++i)
#pragma unroll
    for (int jn = 0; jn < 4; ++jn) {
      int gcol = bx * 128 + wc * 64 + jn * 16 + (lane & 15);
      float bias = b_ih[gcol];
#pragma unroll
      for (int r4 = 0; r4 < 4; ++r4) {
        int grow = by * 128 + wr * 64 + i * 16 + (lane >> 4) * 4 + r4;
        gi[(size_t)grow * 768 + gcol] = acc[i][jn][r4] + bias;
      }
    }
}

// ---------------------------------------------------------------------------
// GRU (unchanged): 28 blocks x 512 thr, weights streamed via 2-stage register
// pipeline, gi async-staged into LDS dbuf.
// ---------------------------------------------------------------------------
__global__ __launch_bounds__(512) void gru_fused(
    const u16* __restrict__ whh_pk, const float* __restrict__ b_hh,
    const float* __restrict__ hidden, const float* __restrict__ gi,
    u16* __restrict__ ctxb)
{
  const int n0 = blockIdx.x * 16;
  const int t = threadIdx.x, lane = t & 63, w = t >> 6;

  __shared__ char sm[16384 + 2 * 49152];
  const int GI0 = 16384;

  const int l15 = lane & 15;
  const int seq0 = (lane >> 4) * 4;
  const int hc0 = w * 32 + l15, hc1 = w * 32 + 16 + l15;

  const float br0 = b_hh[hc0],       br1 = b_hh[hc1];
  const float bz0 = b_hh[256 + hc0], bz1 = b_hh[256 + hc1];
  const float bn0 = b_hh[512 + hc0], bn1 = b_hh[512 + hc1];

#pragma unroll
  for (int i = 0; i < 6; ++i) {
    int chunk = w * 6 + i;
    gld_lds16(gi + (size_t)n0 * 768 + chunk * 256 + lane * 4,
              sm + GI0 + chunk * 1024);
  }

  float hold[2][4];
  {
    float h0 = hidden[hc0], h1 = hidden[hc1];
#pragma unroll
    for (int r4 = 0; r4 < 4; ++r4) { hold[0][r4] = h0; hold[1][r4] = h1; }
    u16 hb0 = f2bf(h0), hb1 = f2bf(h1);
#pragma unroll
    for (int r4 = 0; r4 < 4; ++r4) {
      int seq = seq0 + r4;
      *(u16*)(sm + seq * 512 + ((hc0 * 2) ^ ((seq & 7) << 4))) = hb0;
      *(u16*)(sm + seq * 512 + ((hc1 * 2) ^ ((seq & 7) << 4))) = hb1;
    }
  }
  __syncthreads();

  for (int r = 0; r < 6; ++r) {
    const char* hb  = sm + (r & 1) * 8192;
    char* hbn       = sm + ((r + 1) & 1) * 8192;
    const char* gbr = sm + GI0 + (r & 1) * 49152;

    if (r + 1 < 6) {
#pragma unroll
      for (int i = 0; i < 6; ++i) {
        int chunk = w * 6 + i;
        gld_lds16(gi + (size_t)((r + 1) * 448 + n0) * 768 + chunk * 256 + lane * 4,
                  sm + GI0 + ((r + 1) & 1) * 49152 + chunk * 1024);
      }
    }

    uintptr_t pa = (uintptr_t)whh_pk;
    asm volatile("" : "+v"(pa));
    const char* pkb = (const char*)pa + w * 49152 + lane * 16;

    f32x4 acc[6];
#pragma unroll
    for (int nf = 0; nf < 6; ++nf) acc[nf] = (f32x4){0.f, 0.f, 0.f, 0.f};

    bf16x8 bA[6], bB[6];
#pragma unroll
    for (int nf = 0; nf < 6; ++nf) bA[nf] = *(const bf16x8*)(pkb + nf * 8192);
#pragma unroll
    for (int kp = 0; kp < 4; ++kp) {
      const int ks0 = kp * 2, ks1 = kp * 2 + 1;
#pragma unroll
      for (int nf = 0; nf < 6; ++nf)
        bB[nf] = *(const bf16x8*)(pkb + nf * 8192 + ks1 * 1024);
      {
        bf16x8 a = lds_frag(hb, l15 * 512 +
                            ((ks0 * 64 + (lane >> 4) * 16) ^ ((l15 & 7) << 4)));
#pragma unroll
        for (int nf = 0; nf < 6; ++nf) acc[nf] = MFMA16(a, bA[nf], acc[nf]);
      }
      if (kp < 3) {
#pragma unroll
        for (int nf = 0; nf < 6; ++nf)
          bA[nf] = *(const bf16x8*)(pkb + nf * 8192 + (ks0 + 2) * 1024);
      }
      {
        bf16x8 a = lds_frag(hb, l15 * 512 +
                            ((ks1 * 64 + (lane >> 4) * 16) ^ ((l15 & 7) << 4)));
#pragma unroll
        for (int nf = 0; nf < 6; ++nf) acc[nf] = MFMA16(a, bB[nf], acc[nf]);
      }
    }

    __syncthreads();

#pragma unroll
    for (int r4 = 0; r4 < 4; ++r4) {
      int seq = seq0 + r4;
      float ir0 = *(const float*)(gbr + (size_t)(seq * 768 + hc0) * 4);
      float iz0 = *(const float*)(gbr + (size_t)(seq * 768 + 256 + hc0) * 4);
      float in0 = *(const float*)(gbr + (size_t)(seq * 768 + 512 + hc0) * 4);
      float ir1 = *(const float*)(gbr + (size_t)(seq * 768 + hc1) * 4);
      float iz1 = *(const float*)(gbr + (size_t)(seq * 768 + 256 + hc1) * 4);
      float in1 = *(const float*)(gbr + (size_t)(seq * 768 + 512 + hc1) * 4);
      {
        float rg = 1.f / (1.f + expf(-(ir0 + acc[0][r4] + br0)));
        float zg = 1.f / (1.f + expf(-(iz0 + acc[2][r4] + bz0)));
        float ng = tanhf(in0 + rg * (acc[4][r4] + bn0));
        float hnew = (1.f - zg) * ng + zg * hold[0][r4];
        hold[0][r4] = hnew;
        u16 hb16 = f2bf(hnew);
        *(u16*)(hbn + seq * 512 + ((hc0 * 2) ^ ((seq & 7) << 4))) = hb16;
        ctxb[(size_t)(r * 448 + n0 + seq) * 256 + hc0] = hb16;
      }
      {
        float rg = 1.f / (1.f + expf(-(ir1 + acc[1][r4] + br1)));
        float zg = 1.f / (1.f + expf(-(iz1 + acc[3][r4] + bz1)));
        float ng = tanhf(in1 + rg * (acc[5][r4] + bn1));
        float hnew = (1.f - zg) * ng + zg * hold[1][r4];
        hold[1][r4] = hnew;
        u16 hb16 = f2bf(hnew);
        *(u16*)(hbn + seq * 512 + ((hc1 * 2) ^ ((seq & 7) << 4))) = hb16;
        ctxb[(size_t)(r * 448 + n0 + seq) * 256 + hc1] = hb16;
      }
    }
    __syncthreads();
  }
}

// ---------------------------------------------------------------------------
// Fused preds+dots v2 (unchanged from round 8): W/E register-direct from
// packed L2-hot buffers; only P through LDS, double-buffered, 1 barrier/chunk.
// ---------------------------------------------------------------------------
__global__ __launch_bounds__(256) void fused_pd(
    const u16* __restrict__ ctxb, const u16* __restrict__ wkwpk,
    const float* __restrict__ wk_b, const u16* __restrict__ epk,
    float* __restrict__ dots)
{
  const int b = blockIdx.x;
  const int s = blockIdx.y;
  const int Ms = (6 - s) * 7;
  const int t = threadIdx.x;
  const int lane = t & 63, w = t >> 6;

  __shared__ uint4 smem4[36864 / 16];   // ctx 24576 | Pt dbuf 2x6144
  char* sm = (char*)smem4;
  const int PT_OFF = 24576;

#pragma unroll
  for (int j = 0; j < 6; ++j) {
    int u = j * 256 + t;
    int row = u >> 5, slot = u & 31;
    int rr = row < Ms ? row : 0;
    int r = rr / 7, c = rr - r * 7;
    uint4 v = *(const uint4*)&ctxb[((size_t)(r * 448 + b * 7 + c)) * 256 + slot * 8];
    int off = row * 512 + ((slot * 16) ^ ((row & 7) << 4));
    *(uint4*)(sm + off) = v;
  }
  __syncthreads();

  bf16x8 a1[3][8];
#pragma unroll
  for (int m = 0; m < 3; ++m)
#pragma unroll
    for (int ks = 0; ks < 8; ++ks) {
      int row = m * 16 + (lane & 15);
      int kb  = (ks * 64 + (lane >> 4) * 16) ^ ((row & 7) << 4);
      a1[m][ks] = lds_frag(sm, row * 512 + kb);
    }

  f32x4 acc2[3];
#pragma unroll
  for (int m = 0; m < 3; ++m) acc2[m] = (f32x4){0.f, 0.f, 0.f, 0.f};

  const char* wfB = (const char*)wkwpk + ((size_t)(s * 20) * 4 + w) * 8192 + lane * 16;
  const char* efB = (const char*)epk   + ((size_t)(b * 20) * 4 + w) * 2048 + lane * 16;
  const int colL = w * 16 + (lane & 15);

  for (int ch = 0; ch < 20; ++ch) {
    const char* wf = wfB + (size_t)ch * 4 * 8192;
    char* pt = sm + PT_OFF + (ch & 1) * 6144;

    f32x4 acc1[3];
#pragma unroll
    for (int m = 0; m < 3; ++m) acc1[m] = (f32x4){0.f, 0.f, 0.f, 0.f};
#pragma unroll
    for (int ks = 0; ks < 8; ++ks) {
      bf16x8 bW = *(const bf16x8*)(wf + ks * 1024);
      acc1[0] = MFMA16(a1[0][ks], bW, acc1[0]);
      acc1[1] = MFMA16(a1[1][ks], bW, acc1[1]);
      acc1[2] = MFMA16(a1[2][ks], bW, acc1[2]);
    }
    {
      float bias = wk_b[s * 1280 + ch * 64 + colL];
#pragma unroll
      for (int m = 0; m < 3; ++m)
#pragma unroll
        for (int r4 = 0; r4 < 4; ++r4) {
          float p = acc1[m][r4] + bias;
          p = fminf(fmaxf(p, -1.f), 1.f);
          int prow = m * 16 + (lane >> 4) * 4 + r4;
          *(u16*)(pt + prow * 128 + ((colL * 2) ^ ((prow & 7) << 4))) = f2bf(p);
        }
    }
    __syncthreads();

    const char* ef = efB + (size_t)ch * 4 * 2048;
#pragma unroll
    for (int ks2 = 0; ks2 < 2; ++ks2) {
      bf16x8 eB = *(const bf16x8*)(ef + ks2 * 1024);
#pragma unroll
      for (int m = 0; m < 3; ++m) {
        int prow = m * 16 + (lane & 15);
        bf16x8 pf = lds_frag(pt, prow * 128 +
                             ((ks2 * 64 + (lane >> 4) * 16) ^ ((prow & 7) << 4)));
        acc2[m] = MFMA16(pf, eB, acc2[m]);
      }
    }
  }

#pragma unroll
  for (int m = 0; m < 3; ++m)
#pragma unroll
    for (int r4 = 0; r4 < 4; ++r4) {
      int row = m * 16 + (lane >> 4) * 4 + r4;
      int q = w * 16 + (lane & 15);
      if (row < Ms && q < 49)
        dots[((size_t)(b * 5 + s) * 42 + row) * 49 + q] = acc2[m][r4];
    }
}

// ---------------------------------------------------------------------------
// Loss + accuracy -> directly into d_out[2] (pre-zeroed), scaled by 1/8960
// ---------------------------------------------------------------------------
__global__ __launch_bounds__(256) void loss_kernel(
    const float* __restrict__ dots, const int* __restrict__ neg_rows,
    const int* __restrict__ neg_cols, float* __restrict__ out)
{
  int gid = blockIdx.x * 256 + threadIdx.x;
  float lsum = 0.f, csum = 0.f;
  if (gid < 8960) {
    int b = gid / 140;
    int rem = gid % 140;
    int p = rem / 7, c = rem % 7;
    int s, r;
    if      (p < 6)  { s = 0; r = p; }
    else if (p < 11) { s = 1; r = p - 6; }
    else if (p < 15) { s = 2; r = p - 11; }
    else if (p < 18) { s = 3; r = p - 15; }
    else             { s = 4; r = p - 18; }

    const float* drow = &dots[((size_t)(b * 5 + s) * 42 + r * 7 + c) * 49];
    float d[17];
    d[0] = drow[r * 7 + c];
    const int nbase = (((b * 5 + s) * 6 + r) * 7 + c) * 16;
#pragma unroll
    for (int j = 0; j < 16; ++j) {
      int q = neg_rows[nbase + j] * 7 + neg_cols[nbase + j];
      d[1 + j] = drow[q];
    }
    float m = d[0];
#pragma unroll
    for (int j = 1; j < 17; ++j) m = fmaxf(m, d[j]);
    float se = 0.f;
#pragma unroll
    for (int j = 0; j < 17; ++j) se += expf(d[j] - m);
    lsum = -(d[0] - m - logf(se));
    csum = (d[0] >= m) ? 1.f : 0.f;
  }

#pragma unroll
  for (int off = 32; off > 0; off >>= 1) {
    lsum += __shfl_down(lsum, off);
    csum += __shfl_down(csum, off);
  }
  __shared__ float red[8];
  int wid = threadIdx.x >> 6;
  if ((threadIdx.x & 63) == 0) { red[wid * 2] = lsum; red[wid * 2 + 1] = csum; }
  __syncthreads();
  if (threadIdx.x == 0) {
    atomicAdd(&out[0], (red[0] + red[2] + red[4] + red[6]) * (1.f / 8960.f));
    atomicAdd(&out[1], (red[1] + red[3] + red[5] + red[7]) * (1.f / 8960.f));
  }
}

// ---------------------------------------------------------------------------
extern "C" void kernel_launch(void* const* d_in, const int* in_sizes, int n_in,
                              void* d_out, int out_size, void* d_ws, size_t ws_size,
                              hipStream_t stream)
{
  const float* enc    = (const float*)d_in[0];
  const float* hidden = (const float*)d_in[1];
  const float* w_ih   = (const float*)d_in[2];
  const float* w_hh   = (const float*)d_in[3];
  const float* b_ih   = (const float*)d_in[4];
  const float* b_hh   = (const float*)d_in[5];
  const float* wk_w   = (const float*)d_in[6];
  const float* wk_b   = (const float*)d_in[7];
  const int* neg_rows = (const int*)d_in[8];
  const int* neg_cols = (const int*)d_in[9];
  float* out = (float*)d_out;

  float* ws    = (float*)d_ws;
  float* gi    = ws;                                // [6*448][768] f32
  u16*   ctxb  = (u16*)(gi + 6 * 448 * 768);        // [6*448][256] bf16
  u16*   whhpk = ctxb + 6 * 448 * 256;              // 196608 bf16
  u16*   wkwpk = whhpk + 24576 * 8;                 // 1638400 bf16
  u16*   epk   = wkwpk + 204800 * 8;                // 5242880 bf16
  u16*   enc2  = epk + 655360 * 8;                  // 3440640 bf16
  u16*   wih2  = enc2 + 430080 * 8;                 // 983040 bf16
  float* dotsb = (float*)(wih2 + 122880 * 8);       // [64][5][42][49] f32

  hipMemsetAsync(out, 0, 2 * sizeof(float), stream);

  pack_all<<<5616, 256, 0, stream>>>(w_hh, wk_w, enc, w_ih,
                                     whhpk, wkwpk, epk, enc2, wih2);

  gi_mfma<<<dim3(6, 21), 256, 0, stream>>>(enc2, wih2, b_ih, gi);

  gru_fused<<<28, 512, 0, stream>>>(whhpk, b_hh, hidden, gi, ctxb);

  fused_pd<<<dim3(64, 5), 256, 0, stream>>>(ctxb, wkwpk, wk_b, epk, dotsb);

  loss_kernel<<<35, 256, 0, stream>>>(dotsb, neg_rows, neg_cols, out);
}

// Round 10
// 113.265 us; speedup vs baseline: 1.5124x; 1.1243x over previous
//
#include <hip/hip_runtime.h>
#include <math.h>

// B=64, ROWS=7, COLS=7, D=1280, H=256, S=5, NEG=16, GRU_ROWS=6
// valid (s,r): r < 6-s -> 20 pairs; num_preds = 20*64*7 = 8960

typedef __bf16 bf16x8 __attribute__((ext_vector_type(8)));
typedef float  f32x4  __attribute__((ext_vector_type(4)));
typedef unsigned short u16;
typedef unsigned int u32;

__device__ inline u16 f2bf(float f) {           // RNE f32 -> bf16 bits
  unsigned int u = __float_as_uint(f);
  u += 0x7fff + ((u >> 16) & 1);
  return (u16)(u >> 16);
}

__device__ inline float bf2f(u16 b) {
  u32 u = (u32)b << 16;
  return __builtin_bit_cast(float, u);
}

__device__ inline void f2bf8(const float* s, u16* o) {
  float4 v0 = *(const float4*)s, v1 = *(const float4*)(s + 4);
  o[0] = f2bf(v0.x); o[1] = f2bf(v0.y); o[2] = f2bf(v0.z); o[3] = f2bf(v0.w);
  o[4] = f2bf(v1.x); o[5] = f2bf(v1.y); o[6] = f2bf(v1.z); o[7] = f2bf(v1.w);
}

__device__ inline bf16x8 lds_frag(const char* sm, int off) {
  return __builtin_bit_cast(bf16x8, *(const uint4*)(sm + off));
}

// async global->LDS 16B per lane (wave-uniform LDS base, per-lane global src)
__device__ inline void gld_lds16(const void* g, void* l) {
  __builtin_amdgcn_global_load_lds(
      (const __attribute__((address_space(1))) u32*)g,
      (__attribute__((address_space(3))) u32*)l, 16, 0, 0);
}

// fast gates: v_exp_f32 + v_rcp_f32 (error ~1e-7, fine vs bf16 pipeline)
__device__ inline float fast_sigmoid(float x) {
  float t = __builtin_amdgcn_exp2f(-1.44269504f * x);
  return __builtin_amdgcn_rcpf(1.f + t);
}
__device__ inline float fast_tanh(float x) {
  float xc = fminf(fmaxf(x, -9.f), 9.f);
  float t = __builtin_amdgcn_exp2f(2.88539008f * xc);   // e^{2x}
  return (t - 1.f) * __builtin_amdgcn_rcpf(t + 1.f);
}

#define MFMA16(a, b, c) __builtin_amdgcn_mfma_f32_16x16x32_bf16(a, b, c, 0, 0, 0)

// ---------------------------------------------------------------------------
// pack_all: one pass producing all fragment/staging-ordered bf16 buffers,
// and zeroing out[2] (replaces a hipMemsetAsync dispatch; stream order
// guarantees it lands before loss_kernel's atomics).
// ---------------------------------------------------------------------------
__global__ __launch_bounds__(256) void pack_all(
    const float* __restrict__ w_hh, const float* __restrict__ wk_w,
    const float* __restrict__ enc,  const float* __restrict__ w_ih,
    u16* __restrict__ whhpk, u16* __restrict__ wkwpk, u16* __restrict__ epk,
    u16* __restrict__ enc2,  u16* __restrict__ wih2, float* __restrict__ out)
{
  int tid = blockIdx.x * 256 + threadIdx.x;
  int lane = tid & 63;
  if (tid == 0) { out[0] = 0.f; out[1] = 0.f; }
  u16 o[8];
  if (tid < 24576) {
    int rest = tid >> 6;                       // cb*8 + ks
    int cb = rest >> 3, ks = rest & 7;
    int w = cb / 6, nf = cb % 6;
    int g = nf >> 1, half = nf & 1;
    int col = g * 256 + w * 32 + half * 16 + (lane & 15);
    int k = ks * 32 + (lane >> 4) * 8;
    f2bf8(&w_hh[(size_t)col * 256 + k], o);
    *(uint4*)&whhpk[(size_t)tid * 8] = *(uint4*)o;
  } else if (tid < 229376) {
    int u = tid - 24576;
    int f = u >> 6;
    int ks = f & 7, t1 = f >> 3;
    int w = t1 & 3, t2 = t1 >> 2;
    int ch = t2 % 20, s = t2 / 20;
    f2bf8(&wk_w[((size_t)s * 1280 + ch * 64 + w * 16 + (lane & 15)) * 256
                + ks * 32 + (lane >> 4) * 8], o);
    *(uint4*)&wkwpk[(size_t)f * 512 + lane * 8] = *(uint4*)o;
  } else if (tid < 884736) {
    int u = tid - 229376;
    int f = u >> 6;
    int ks2 = f & 1, t1 = f >> 1;
    int w = t1 & 3, t2 = t1 >> 2;
    int ch = t2 % 20, b = t2 / 20;
    int q = w * 16 + (lane & 15);
    if (q < 49) {
      f2bf8(&enc[(size_t)(b * 49 + q) * 1280 + ch * 64 + ks2 * 32 + (lane >> 4) * 8], o);
    } else {
#pragma unroll
      for (int j = 0; j < 8; ++j) o[j] = 0;
    }
    *(uint4*)&epk[(size_t)f * 512 + lane * 8] = *(uint4*)o;
  } else if (tid < 1314816) {
    int u = tid - 884736;                      // (by*20+k0)*1024 + row*8 + sl
    int unit = u & 1023;
    int row = unit >> 3, sl = unit & 7;
    int tk = u >> 10;
    int k0 = tk % 20, by = tk / 20;
    int m = by * 128 + row;
    int r = m / 448, n = m - r * 448;
    int b = n / 7, c = n - b * 7;
    int slot = sl ^ (row & 7);                 // inverse-swizzle the source
    f2bf8(&enc[(size_t)(b * 49 + r * 7 + c) * 1280 + k0 * 64 + slot * 8], o);
    *(uint4*)&enc2[(size_t)u * 8] = *(uint4*)o;
  } else if (tid < 1437696) {
    int u = tid - 1314816;                     // (bx*20+k0)*1024 + row*8 + sl
    int unit = u & 1023;
    int row = unit >> 3, sl = unit & 7;
    int tk = u >> 10;
    int k0 = tk % 20, bx = tk / 20;
    int slot = sl ^ (row & 7);
    f2bf8(&w_ih[(size_t)(bx * 128 + row) * 1280 + k0 * 64 + slot * 8], o);
    *(uint4*)&wih2[(size_t)u * 8] = *(uint4*)o;
  }
}

// ---------------------------------------------------------------------------
// gi = enc @ w_ih^T + b_ih via bf16 MFMA; operands pre-swizzled in global
// (enc2/wih2) -> staging is pure global_load_lds. OUTPUT NOW bf16 (gib).
// ---------------------------------------------------------------------------
__global__ __launch_bounds__(256) void gi_mfma(
    const u16* __restrict__ enc2, const u16* __restrict__ wih2,
    const float* __restrict__ b_ih, u16* __restrict__ gib)
{
  const int bx = blockIdx.x, by = blockIdx.y;
  const int t = threadIdx.x, lane = t & 63, w = t >> 6;
  const int wr = w >> 1, wc = w & 1;

  __shared__ char sm[32768];
  const int A_OFF = 0, B_OFF = 16384;
  const int wu = t & ~63;   // wave-uniform thread base

  f32x4 acc[4][4];
#pragma unroll
  for (int i = 0; i < 4; ++i)
#pragma unroll
    for (int j = 0; j < 4; ++j) acc[i][j] = (f32x4){0.f, 0.f, 0.f, 0.f};

  for (int k0c = 0; k0c < 20; ++k0c) {
    if (k0c) __syncthreads();
    const char* ga = (const char*)enc2 + ((size_t)(by * 20 + k0c) << 14);
    const char* gb = (const char*)wih2 + ((size_t)(bx * 20 + k0c) << 14);
#pragma unroll
    for (int j = 0; j < 4; ++j) {
      gld_lds16(ga + (j * 256 + t) * 16, sm + A_OFF + (j * 256 + wu) * 16);
      gld_lds16(gb + (j * 256 + t) * 16, sm + B_OFF + (j * 256 + wu) * 16);
    }
    __syncthreads();   // implicit vmcnt(0) drain covers global_load_lds
#pragma unroll
    for (int ks = 0; ks < 2; ++ks) {
      bf16x8 a[4], b[4];
#pragma unroll
      for (int i = 0; i < 4; ++i) {
        int arow = wr * 64 + i * 16 + (lane & 15);
        int akb  = (ks * 64 + (lane >> 4) * 16) ^ ((arow & 7) << 4);
        a[i] = lds_frag(sm, A_OFF + arow * 128 + akb);
        int brow = wc * 64 + i * 16 + (lane & 15);
        int bkb  = (ks * 64 + (lane >> 4) * 16) ^ ((brow & 7) << 4);
        b[i] = lds_frag(sm, B_OFF + brow * 128 + bkb);
      }
#pragma unroll
      for (int i = 0; i < 4; ++i)
#pragma unroll
        for (int jn = 0; jn < 4; ++jn)
          acc[i][jn] = MFMA16(a[i], b[jn], acc[i][jn]);
    }
  }

#pragma unroll
  for (int i = 0; i < 4; ++i)
#pragma unroll
    for (int jn = 0; jn < 4; ++jn) {
      int gcol = bx * 128 + wc * 64 + jn * 16 + (lane & 15);
      float bias = b_ih[gcol];
#pragma unroll
      for (int r4 = 0; r4 < 4; ++r4) {
        int grow = by * 128 + wr * 64 + i * 16 + (lane >> 4) * 4 + r4;
        gib[(size_t)grow * 768 + gcol] = f2bf(acc[i][jn][r4] + bias);
      }
    }
}

// ---------------------------------------------------------------------------
// GRU: 28 blocks x 512 thr (8 waves), 16 seqs/block. Round-10 changes:
//  - fast exp2/rcp gates (libm tanhf/expf was ~37% local VALUBusy)
//  - ONE barrier per step (post-MFMA barrier removed; h + gi double-buffered)
//  - gi is bf16 (half the prefetch bytes), prefetch issued AFTER the MFMA
//    phase so weight-load vmcnt waits don't queue behind it (in-order retire)
// ---------------------------------------------------------------------------
__global__ __launch_bounds__(512) void gru_fused(
    const u16* __restrict__ whh_pk, const float* __restrict__ b_hh,
    const float* __restrict__ hidden, const u16* __restrict__ gib,
    u16* __restrict__ ctxb)
{
  const int n0 = blockIdx.x * 16;
  const int t = threadIdx.x, lane = t & 63, w = t >> 6;

  __shared__ char sm[16384 + 2 * 24576];   // h dbuf 2x8KB | gi dbuf 2x24KB
  const int GI0 = 16384;

  const int l15 = lane & 15;
  const int seq0 = (lane >> 4) * 4;
  const int hc0 = w * 32 + l15, hc1 = w * 32 + 16 + l15;

  const float br0 = b_hh[hc0],       br1 = b_hh[hc1];
  const float bz0 = b_hh[256 + hc0], bz1 = b_hh[256 + hc1];
  const float bn0 = b_hh[512 + hc0], bn1 = b_hh[512 + hc1];

  // stage gi[0] (bf16, 24KB): 3 x 1KB chunks per wave
#pragma unroll
  for (int i = 0; i < 3; ++i) {
    int chunk = w * 3 + i;
    gld_lds16(gib + (size_t)n0 * 768 + chunk * 512 + lane * 8,
              sm + GI0 + chunk * 1024);
  }

  float hold[2][4];
  {
    float h0 = hidden[hc0], h1 = hidden[hc1];
#pragma unroll
    for (int r4 = 0; r4 < 4; ++r4) { hold[0][r4] = h0; hold[1][r4] = h1; }
    u16 hb0 = f2bf(h0), hb1 = f2bf(h1);
#pragma unroll
    for (int r4 = 0; r4 < 4; ++r4) {
      int seq = seq0 + r4;
      *(u16*)(sm + seq * 512 + ((hc0 * 2) ^ ((seq & 7) << 4))) = hb0;
      *(u16*)(sm + seq * 512 + ((hc1 * 2) ^ ((seq & 7) << 4))) = hb1;
    }
  }
  __syncthreads();   // drains gi[0] prefetch + h init

  for (int r = 0; r < 6; ++r) {
    const char* hb  = sm + (r & 1) * 8192;
    char* hbn       = sm + ((r + 1) & 1) * 8192;
    const char* gbr = sm + GI0 + (r & 1) * 24576;

    uintptr_t pa = (uintptr_t)whh_pk;
    asm volatile("" : "+v"(pa));        // defeat cross-step load hoisting
    const char* pkb = (const char*)pa + w * 49152 + lane * 16;

    f32x4 acc[6];
#pragma unroll
    for (int nf = 0; nf < 6; ++nf) acc[nf] = (f32x4){0.f, 0.f, 0.f, 0.f};

    // 2-stage weight pipeline over ks (all static indexing)
    bf16x8 bA[6], bB[6];
#pragma unroll
    for (int nf = 0; nf < 6; ++nf) bA[nf] = *(const bf16x8*)(pkb + nf * 8192);
#pragma unroll
    for (int kp = 0; kp < 4; ++kp) {
      const int ks0 = kp * 2, ks1 = kp * 2 + 1;
#pragma unroll
      for (int nf = 0; nf < 6; ++nf)
        bB[nf] = *(const bf16x8*)(pkb + nf * 8192 + ks1 * 1024);
      {
        bf16x8 a = lds_frag(hb, l15 * 512 +
                            ((ks0 * 64 + (lane >> 4) * 16) ^ ((l15 & 7) << 4)));
#pragma unroll
        for (int nf = 0; nf < 6; ++nf) acc[nf] = MFMA16(a, bA[nf], acc[nf]);
      }
      if (kp < 3) {
#pragma unroll
        for (int nf = 0; nf < 6; ++nf)
          bA[nf] = *(const bf16x8*)(pkb + nf * 8192 + (ks0 + 2) * 1024);
      }
      {
        bf16x8 a = lds_frag(hb, l15 * 512 +
                            ((ks1 * 64 + (lane >> 4) * 16) ^ ((l15 & 7) << 4)));
#pragma unroll
        for (int nf = 0; nf < 6; ++nf) acc[nf] = MFMA16(a, bB[nf], acc[nf]);
      }
    }

    // prefetch gi[r+1] AFTER the MFMA phase: weight waits above never queue
    // behind this HBM-latency load; it drains at the step-end barrier.
    if (r + 1 < 6) {
#pragma unroll
      for (int i = 0; i < 3; ++i) {
        int chunk = w * 3 + i;
        gld_lds16(gib + (size_t)((r + 1) * 448 + n0) * 768 + chunk * 512 + lane * 8,
                  sm + GI0 + ((r + 1) & 1) * 24576 + chunk * 1024);
      }
    }

    // pointwise in registers (gi[r] from LDS was drained by PREVIOUS barrier)
#pragma unroll
    for (int r4 = 0; r4 < 4; ++r4) {
      int seq = seq0 + r4;
      float ir0 = bf2f(*(const u16*)(gbr + (size_t)(seq * 768 + hc0) * 2));
      float iz0 = bf2f(*(const u16*)(gbr + (size_t)(seq * 768 + 256 + hc0) * 2));
      float in0 = bf2f(*(const u16*)(gbr + (size_t)(seq * 768 + 512 + hc0) * 2));
      float ir1 = bf2f(*(const u16*)(gbr + (size_t)(seq * 768 + hc1) * 2));
      float iz1 = bf2f(*(const u16*)(gbr + (size_t)(seq * 768 + 256 + hc1) * 2));
      float in1 = bf2f(*(const u16*)(gbr + (size_t)(seq * 768 + 512 + hc1) * 2));
      {
        float rg = fast_sigmoid(ir0 + acc[0][r4] + br0);
        float zg = fast_sigmoid(iz0 + acc[2][r4] + bz0);
        float ng = fast_tanh(in0 + rg * (acc[4][r4] + bn0));
        float hnew = (1.f - zg) * ng + zg * hold[0][r4];
        hold[0][r4] = hnew;
        u16 hb16 = f2bf(hnew);
        *(u16*)(hbn + seq * 512 + ((hc0 * 2) ^ ((seq & 7) << 4))) = hb16;
        ctxb[(size_t)(r * 448 + n0 + seq) * 256 + hc0] = hb16;
      }
      {
        float rg = fast_sigmoid(ir1 + acc[1][r4] + br1);
        float zg = fast_sigmoid(iz1 + acc[3][r4] + bz1);
        float ng = fast_tanh(in1 + rg * (acc[5][r4] + bn1));
        float hnew = (1.f - zg) * ng + zg * hold[1][r4];
        hold[1][r4] = hnew;
        u16 hb16 = f2bf(hnew);
        *(u16*)(hbn + seq * 512 + ((hc1 * 2) ^ ((seq & 7) << 4))) = hb16;
        ctxb[(size_t)(r * 448 + n0 + seq) * 256 + hc1] = hb16;
      }
    }
    __syncthreads();   // single barrier/step: drains gi[r+1] + hbn writes
  }
}

// ---------------------------------------------------------------------------
// Fused preds+dots v2 (unchanged): W/E register-direct from packed L2-hot
// buffers; only P through LDS, double-buffered, 1 barrier/chunk.
// ---------------------------------------------------------------------------
__global__ __launch_bounds__(256) void fused_pd(
    const u16* __restrict__ ctxb, const u16* __restrict__ wkwpk,
    const float* __restrict__ wk_b, const u16* __restrict__ epk,
    float* __restrict__ dots)
{
  const int b = blockIdx.x;
  const int s = blockIdx.y;
  const int Ms = (6 - s) * 7;
  const int t = threadIdx.x;
  const int lane = t & 63, w = t >> 6;

  __shared__ uint4 smem4[36864 / 16];   // ctx 24576 | Pt dbuf 2x6144
  char* sm = (char*)smem4;
  const int PT_OFF = 24576;

#pragma unroll
  for (int j = 0; j < 6; ++j) {
    int u = j * 256 + t;
    int row = u >> 5, slot = u & 31;
    int rr = row < Ms ? row : 0;
    int r = rr / 7, c = rr - r * 7;
    uint4 v = *(const uint4*)&ctxb[((size_t)(r * 448 + b * 7 + c)) * 256 + slot * 8];
    int off = row * 512 + ((slot * 16) ^ ((row & 7) << 4));
    *(uint4*)(sm + off) = v;
  }
  __syncthreads();

  bf16x8 a1[3][8];
#pragma unroll
  for (int m = 0; m < 3; ++m)
#pragma unroll
    for (int ks = 0; ks < 8; ++ks) {
      int row = m * 16 + (lane & 15);
      int kb  = (ks * 64 + (lane >> 4) * 16) ^ ((row & 7) << 4);
      a1[m][ks] = lds_frag(sm, row * 512 + kb);
    }

  f32x4 acc2[3];
#pragma unroll
  for (int m = 0; m < 3; ++m) acc2[m] = (f32x4){0.f, 0.f, 0.f, 0.f};

  const char* wfB = (const char*)wkwpk + ((size_t)(s * 20) * 4 + w) * 8192 + lane * 16;
  const char* efB = (const char*)epk   + ((size_t)(b * 20) * 4 + w) * 2048 + lane * 16;
  const int colL = w * 16 + (lane & 15);

  for (int ch = 0; ch < 20; ++ch) {
    const char* wf = wfB + (size_t)ch * 4 * 8192;
    char* pt = sm + PT_OFF + (ch & 1) * 6144;

    f32x4 acc1[3];
#pragma unroll
    for (int m = 0; m < 3; ++m) acc1[m] = (f32x4){0.f, 0.f, 0.f, 0.f};
#pragma unroll
    for (int ks = 0; ks < 8; ++ks) {
      bf16x8 bW = *(const bf16x8*)(wf + ks * 1024);
      acc1[0] = MFMA16(a1[0][ks], bW, acc1[0]);
      acc1[1] = MFMA16(a1[1][ks], bW, acc1[1]);
      acc1[2] = MFMA16(a1[2][ks], bW, acc1[2]);
    }
    {
      float bias = wk_b[s * 1280 + ch * 64 + colL];
#pragma unroll
      for (int m = 0; m < 3; ++m)
#pragma unroll
        for (int r4 = 0; r4 < 4; ++r4) {
          float p = acc1[m][r4] + bias;
          p = fminf(fmaxf(p, -1.f), 1.f);
          int prow = m * 16 + (lane >> 4) * 4 + r4;
          *(u16*)(pt + prow * 128 + ((colL * 2) ^ ((prow & 7) << 4))) = f2bf(p);
        }
    }
    __syncthreads();

    const char* ef = efB + (size_t)ch * 4 * 2048;
#pragma unroll
    for (int ks2 = 0; ks2 < 2; ++ks2) {
      bf16x8 eB = *(const bf16x8*)(ef + ks2 * 1024);
#pragma unroll
      for (int m = 0; m < 3; ++m) {
        int prow = m * 16 + (lane & 15);
        bf16x8 pf = lds_frag(pt, prow * 128 +
                             ((ks2 * 64 + (lane >> 4) * 16) ^ ((prow & 7) << 4)));
        acc2[m] = MFMA16(pf, eB, acc2[m]);
      }
    }
  }

#pragma unroll
  for (int m = 0; m < 3; ++m)
#pragma unroll
    for (int r4 = 0; r4 < 4; ++r4) {
      int row = m * 16 + (lane >> 4) * 4 + r4;
      int q = w * 16 + (lane & 15);
      if (row < Ms && q < 49)
        dots[((size_t)(b * 5 + s) * 42 + row) * 49 + q] = acc2[m][r4];
    }
}

// ---------------------------------------------------------------------------
// Loss + accuracy -> directly into d_out[2] (zeroed by pack_all), /8960
// ---------------------------------------------------------------------------
__global__ __launch_bounds__(256) void loss_kernel(
    const float* __restrict__ dots, const int* __restrict__ neg_rows,
    const int* __restrict__ neg_cols, float* __restrict__ out)
{
  int gid = blockIdx.x * 256 + threadIdx.x;
  float lsum = 0.f, csum = 0.f;
  if (gid < 8960) {
    int b = gid / 140;
    int rem = gid % 140;
    int p = rem / 7, c = rem % 7;
    int s, r;
    if      (p < 6)  { s = 0; r = p; }
    else if (p < 11) { s = 1; r = p - 6; }
    else if (p < 15) { s = 2; r = p - 11; }
    else if (p < 18) { s = 3; r = p - 15; }
    else             { s = 4; r = p - 18; }

    const float* drow = &dots[((size_t)(b * 5 + s) * 42 + r * 7 + c) * 49];
    float d[17];
    d[0] = drow[r * 7 + c];
    const int nbase = (((b * 5 + s) * 6 + r) * 7 + c) * 16;
#pragma unroll
    for (int j = 0; j < 16; ++j) {
      int q = neg_rows[nbase + j] * 7 + neg_cols[nbase + j];
      d[1 + j] = drow[q];
    }
    float m = d[0];
#pragma unroll
    for (int j = 1; j < 17; ++j) m = fmaxf(m, d[j]);
    float se = 0.f;
#pragma unroll
    for (int j = 0; j < 17; ++j) se += expf(d[j] - m);
    lsum = -(d[0] - m - logf(se));
    csum = (d[0] >= m) ? 1.f : 0.f;
  }

#pragma unroll
  for (int off = 32; off > 0; off >>= 1) {
    lsum += __shfl_down(lsum, off);
    csum += __shfl_down(csum, off);
  }
  __shared__ float red[8];
  int wid = threadIdx.x >> 6;
  if ((threadIdx.x & 63) == 0) { red[wid * 2] = lsum; red[wid * 2 + 1] = csum; }
  __syncthreads();
  if (threadIdx.x == 0) {
    atomicAdd(&out[0], (red[0] + red[2] + red[4] + red[6]) * (1.f / 8960.f));
    atomicAdd(&out[1], (red[1] + red[3] + red[5] + red[7]) * (1.f / 8960.f));
  }
}

// ---------------------------------------------------------------------------
extern "C" void kernel_launch(void* const* d_in, const int* in_sizes, int n_in,
                              void* d_out, int out_size, void* d_ws, size_t ws_size,
                              hipStream_t stream)
{
  const float* enc    = (const float*)d_in[0];
  const float* hidden = (const float*)d_in[1];
  const float* w_ih   = (const float*)d_in[2];
  const float* w_hh   = (const float*)d_in[3];
  const float* b_ih   = (const float*)d_in[4];
  const float* b_hh   = (const float*)d_in[5];
  const float* wk_w   = (const float*)d_in[6];
  const float* wk_b   = (const float*)d_in[7];
  const int* neg_rows = (const int*)d_in[8];
  const int* neg_cols = (const int*)d_in[9];
  float* out = (float*)d_out;

  u16*   gib   = (u16*)d_ws;                        // [6*448][768] bf16
  u16*   ctxb  = gib + 6 * 448 * 768;               // [6*448][256] bf16
  u16*   whhpk = ctxb + 6 * 448 * 256;              // 196608 bf16
  u16*   wkwpk = whhpk + 24576 * 8;                 // 1638400 bf16
  u16*   epk   = wkwpk + 204800 * 8;                // 5242880 bf16
  u16*   enc2  = epk + 655360 * 8;                  // 3440640 bf16
  u16*   wih2  = enc2 + 430080 * 8;                 // 983040 bf16
  float* dotsb = (float*)(wih2 + 122880 * 8);       // [64][5][42][49] f32

  pack_all<<<5616, 256, 0, stream>>>(w_hh, wk_w, enc, w_ih,
                                     whhpk, wkwpk, epk, enc2, wih2, out);

  gi_mfma<<<dim3(6, 21), 256, 0, stream>>>(enc2, wih2, b_ih, gib);

  gru_fused<<<28, 512, 0, stream>>>(whhpk, b_hh, hidden, gib, ctxb);

  fused_pd<<<dim3(64, 5), 256, 0, stream>>>(ctxb, wkwpk, wk_b, epk, dotsb);

  loss_kernel<<<35, 256, 0, stream>>>(dotsb, neg_rows, neg_cols, out);
}